// Round 3
// baseline (207.241 us; speedup 1.0000x reference)
//
#include <hip/hip_runtime.h>
#include <hip/hip_bf16.h>

// Problem constants (from reference setup_inputs)
#define B_   16
#define C_   64
#define HW_  65536   // 256*256
#define TILE 128     // pixels per block in fused kernel
#define GB   4       // batches per group (64 MiB working set << 256 MiB L3)
#define NG   (B_ / GB)

typedef float f4_t __attribute__((ext_vector_type(4)));

// fast branch-free tanh: 1 - 2/(e^2z + 1), clamped
__device__ __forceinline__ float fast_tanh(float z) {
    z = fminf(fmaxf(z, -15.f), 15.f);
    float e = __expf(2.f * z);
    return 1.f - 2.f * __builtin_amdgcn_rcpf(e + 1.f);
}

// ---------------------------------------------------------------------------
// Kernel 1 (per group of GB batches): partial sums of x[b,c,:,:], and the
// last-finishing block of each batch (atomic counter) computes the tiny GCN
// math -> w_eff[b,:], bias_eff[b]. Values are deterministic regardless of
// which block finishes last.
// grid = GB*64*2 = 512 blocks, 256 threads; each block reduces half a channel.
// ---------------------------------------------------------------------------
__global__ __launch_bounds__(256) void k_reduce_group(
    const float* __restrict__ x, int b0,
    const float* __restrict__ theta_w, const float* __restrict__ theta_b,
    const float* __restrict__ g1_w,    const float* __restrict__ g1_b,
    const float* __restrict__ g2_w,    const float* __restrict__ g2_b,
    float* __restrict__ part, float* __restrict__ w_eff,
    float* __restrict__ bias_eff, int* __restrict__ cnt) {
    int t    = threadIdx.x;
    int blk  = blockIdx.x;          // 0..511
    int half = blk & 1;
    int bcl  = blk >> 1;            // 0..255 : bi*64 + c
    int b    = b0 + (bcl >> 6);
    int c    = bcl & 63;
    int bc   = b * C_ + c;

    const float4* p4 = (const float4*)(x + (size_t)bc * HW_ + half * (HW_ / 2));
    float s = 0.f;
#pragma unroll
    for (int i = 0; i < 32; ++i) {
        float4 v = p4[t + 256 * i];
        s += (v.x + v.y) + (v.z + v.w);
    }
#pragma unroll
    for (int off = 32; off; off >>= 1) s += __shfl_down(s, off, 64);

    __shared__ float ls[4];
    __shared__ int amlast;
    int wid = t >> 6, lane = t & 63;
    if (lane == 0) ls[wid] = s;
    __syncthreads();
    if (t == 0) {
        part[bc * 2 + half] = (ls[0] + ls[1]) + (ls[2] + ls[3]);
        __threadfence();                      // release partial
        int old = atomicAdd(&cnt[b], 1);      // device-scope
        amlast = (old == 2 * C_ - 1);
    }
    __syncthreads();
    if (!amlast) return;

    // ---- last block for batch b: tiny GCN math, 256 threads ----
    __threadfence();                          // acquire all partials
    __shared__ float xn[C_], z1s[C_], hp[4][C_], wp[4][C_];
    int n = t & 63, q = t >> 6;
    if (t < C_) {
        float p0 = part[(b * C_ + t) * 2], p1 = part[(b * C_ + t) * 2 + 1];
        xn[t] = (p0 + p1) * (1.0f / (float)HW_);
    }
    __syncthreads();
    float hpart = 0.f;
#pragma unroll
    for (int i = 0; i < 16; ++i) {
        int cc = q * 16 + i;
        hpart += xn[cc] * g1_w[n * C_ + cc];
    }
    hp[q][n] = hpart;
    __syncthreads();
    if (t < C_) {
        float h = g1_b[t] + (hp[0][t] + hp[1][t]) + (hp[2][t] + hp[3][t]);
        z1s[t] = h * g2_w[0] + g2_b[0];
    }
    __syncthreads();
    float wpart = 0.f;
#pragma unroll
    for (int i = 0; i < 16; ++i) {
        int nn = q * 16 + i;
        wpart += z1s[nn] * theta_w[nn * C_ + n];
    }
    wp[q][n] = wpart;
    __syncthreads();
    if (t < C_) w_eff[b * C_ + t] = (wp[0][t] + wp[1][t]) + (wp[2][t] + wp[3][t]);
    if (t == 0) {
        float bb = 0.f;
#pragma unroll
        for (int nn = 0; nn < C_; ++nn) bb += z1s[nn] * theta_b[nn];
        bias_eff[b] = bb;
    }
}

// ---------------------------------------------------------------------------
// Kernel 2 (per group): fused y + phi + tanh, LDS-staged 64x128 tile.
// x reads should hit L3 (just streamed by k_reduce_group); nt stores keep
// the out stream from evicting it.
// grid = GB * (HW/TILE) = 2048 blocks, 256 threads
// ---------------------------------------------------------------------------
__global__ __launch_bounds__(256) void k_fused_out(
    const float* __restrict__ x, int b0,
    const float* __restrict__ w_eff, const float* __restrict__ bias_eff,
    const float* __restrict__ phi_w, const float* __restrict__ phi_b,
    float* __restrict__ out) {
    __shared__ float tile[C_][TILE];   // 32 KiB
    __shared__ float ys[TILE];
    __shared__ float wsh[C_], pw[C_], pb[C_];

    int t  = threadIdx.x;
    int b  = b0 + (blockIdx.x >> 9);   // HW/TILE = 512 tiles per batch
    int ti = blockIdx.x & 511;
    int p0 = ti * TILE;

    if (t < C_) {
        wsh[t] = w_eff[b * C_ + t];
        pw[t]  = phi_w[t];
        pb[t]  = phi_b[t];
    }

    const float* xb = x + (size_t)b * C_ * HW_ + p0;
#pragma unroll
    for (int i = 0; i < 8; ++i) {
        int f = i * 256 + t;
        int c = f >> 5;                // TILE/4 = 32 float4 per channel row
        int j = f & 31;
        float4 v = *(const float4*)(xb + (size_t)c * HW_ + 4 * j);
        *(float4*)&tile[c][4 * j] = v;
    }
    __syncthreads();

    if (t < TILE) {
        float y = bias_eff[b];
#pragma unroll
        for (int c = 0; c < C_; ++c) y += wsh[c] * tile[c][t];
        ys[t] = y;
    }
    __syncthreads();

    float* ob = out + (size_t)b * C_ * HW_ + p0;
#pragma unroll
    for (int i = 0; i < 8; ++i) {
        int f = i * 256 + t;
        int c = f >> 5;
        int j = f & 31;
        float4 v  = *(float4*)&tile[c][4 * j];
        float4 yv = *(float4*)&ys[4 * j];
        float a = pw[c], d = pb[c];
        f4_t r;
        r.x = fast_tanh(yv.x * a + d + v.x);
        r.y = fast_tanh(yv.y * a + d + v.y);
        r.z = fast_tanh(yv.z * a + d + v.z);
        r.w = fast_tanh(yv.w * a + d + v.w);
        __builtin_nontemporal_store(r, (f4_t*)(ob + (size_t)c * HW_ + 4 * j));
    }
}

// ---------------------------------------------------------------------------
extern "C" void kernel_launch(void* const* d_in, const int* in_sizes, int n_in,
                              void* d_out, int out_size, void* d_ws, size_t ws_size,
                              hipStream_t stream) {
    const float* x       = (const float*)d_in[0];
    const float* theta_w = (const float*)d_in[1];
    const float* theta_b = (const float*)d_in[2];
    const float* g1_w    = (const float*)d_in[3];
    const float* g1_b    = (const float*)d_in[4];
    const float* g2_w    = (const float*)d_in[5];
    const float* g2_b    = (const float*)d_in[6];
    const float* phi_w   = (const float*)d_in[7];
    const float* phi_b   = (const float*)d_in[8];
    float* out = (float*)d_out;

    float* part     = (float*)d_ws;                 // B*C*2 floats
    float* w_eff    = part + B_ * C_ * 2;           // B*C floats
    float* bias_eff = w_eff + B_ * C_;              // B floats
    int*   cnt      = (int*)(bias_eff + B_);        // B ints

    hipMemsetAsync(cnt, 0, B_ * sizeof(int), stream);

    for (int g = 0; g < NG; ++g) {
        int b0 = g * GB;
        k_reduce_group<<<GB * C_ * 2, 256, 0, stream>>>(
            x, b0, theta_w, theta_b, g1_w, g1_b, g2_w, g2_b,
            part, w_eff, bias_eff, cnt);
        k_fused_out<<<GB * (HW_ / TILE), 256, 0, stream>>>(
            x, b0, w_eff, bias_eff, phi_w, phi_b, out);
    }
}